// Round 1
// baseline (86229.529 us; speedup 1.0000x reference)
//
#include <hip/hip_runtime.h>
#include <hip/hip_cooperative_groups.h>
#include <math.h>

namespace cg = cooperative_groups;

#define T_  512
#define B_  128
#define H_  256
#define A_  18
#define G4H 1024          // 4*H
#define TB_ (T_*B_)       // 65536

// d_out layout (floats): [logits T*B*A][baseline T*B][action T*B][hT L*B*H][cT L*B*H]
#define OUT_BASE  (TB_*A_)
#define OUT_ACT   (OUT_BASE + TB_)
#define OUT_HT    (OUT_ACT + TB_)
#define OUT_CT    (OUT_HT + 2*B_*H_)

// WG tiling: 16 j-slices (16 h-units -> 64 gate rows/matrix) x 16 batch-slices (8 batches)
// 512 threads = 8 waves; wave q owns k-chunk [32q,32q+32) of each matrix; lane j = local gate row.

__device__ __forceinline__ void compute_partials(
    const float (&wA)[32], const float (&wB)[32],
    const float* __restrict__ tileA, const float* __restrict__ tileB,
    float* __restrict__ part, int q, int j)
{
#pragma unroll 2
    for (int b8 = 0; b8 < 8; ++b8) {
        const float4* pa = (const float4*)&tileA[b8*H_ + q*32];
        const float4* pb = (const float4*)&tileB[b8*H_ + q*32];
        float sa = 0.f, sb2 = 0.f;
#pragma unroll
        for (int kq = 0; kq < 8; ++kq) {
            float4 a4 = pa[kq];
            sa += wA[kq*4+0]*a4.x; sa += wA[kq*4+1]*a4.y;
            sa += wA[kq*4+2]*a4.z; sa += wA[kq*4+3]*a4.w;
            float4 b4 = pb[kq];
            sb2 += wB[kq*4+0]*b4.x; sb2 += wB[kq*4+1]*b4.y;
            sb2 += wB[kq*4+2]*b4.z; sb2 += wB[kq*4+3]*b4.w;
        }
        part[q*576 + j*9 + b8] = sa + sb2;   // j padded by 9 to spread banks
    }
}

__device__ __forceinline__ void head_for(
    int tt, const float* __restrict__ h1full, int b0, int js, int q, int j,
    const float* __restrict__ Wp, const float* __restrict__ bp,
    const float* __restrict__ Wb, const float* __restrict__ bb,
    float* __restrict__ out)
{
    // wave q handles batch b0+q; j-slice js handles output rows js and js+16 (row 18 = baseline)
    float4 hv = *(const float4*)&h1full[(b0 + q)*H_ + j*4];
    for (int aa = js; aa < 19; aa += 16) {
        float4 wv; float bias;
        if (aa < 18) { wv = *(const float4*)&Wp[aa*H_ + j*4]; bias = bp[aa]; }
        else         { wv = *(const float4*)&Wb[j*4];         bias = bb[0]; }
        float p = hv.x*wv.x + hv.y*wv.y + hv.z*wv.z + hv.w*wv.w;
#pragma unroll
        for (int s = 32; s; s >>= 1) p += __shfl_xor(p, s, 64);
        if (j == 0) {
            if (aa < 18) out[(size_t)(tt*B_ + b0 + q)*A_ + aa] = p + bias;
            else         out[OUT_BASE + tt*B_ + b0 + q]        = p + bias;
        }
    }
}

__global__ __launch_bounds__(512, 2) void lstm_scan(
    const float* __restrict__ x, const int* __restrict__ done,
    const float* __restrict__ h0in, const float* __restrict__ c0in,
    const float* __restrict__ w_ih, const float* __restrict__ w_hh,
    const float* __restrict__ b_ih, const float* __restrict__ b_hh,
    const float* __restrict__ Wp, const float* __restrict__ bp,
    const float* __restrict__ Wb, const float* __restrict__ bb,
    float* __restrict__ out, float* __restrict__ h0buf, float* __restrict__ h1buf)
{
    cg::grid_group grid = cg::this_grid();

    const int tid = threadIdx.x;
    const int wg  = blockIdx.x;
    const int js  = wg & 15;          // j-slice
    const int bs  = wg >> 4;          // batch-slice
    const int b0  = bs * 8;
    const int us  = js * 16;          // first h-unit of slice

    const int q = tid >> 6;           // wave id (k-chunk)
    const int j = tid & 63;           // lane = local gate row

    __shared__ __align__(16) float tileA[8*H_];
    __shared__ __align__(16) float tileB[8*H_];
    __shared__ __align__(16) float part[8*576];
    __shared__ __align__(16) float gates[64*8];
    __shared__ float biasS[2*64];
    __shared__ float cs[2*128];

    // ---- persistent weight fragments in VGPRs ----
    const int gate = j >> 4, uu = j & 15;
    const int grow = gate*H_ + us + uu;       // global gate row in [0,1024)
    float w0i[32], w0h[32], w1i[32], w1h[32];
    {
        const float* p = w_ih + (size_t)grow*H_ + q*32;
#pragma unroll
        for (int k = 0; k < 32; ++k) w0i[k] = p[k];
        p = w_hh + (size_t)grow*H_ + q*32;
#pragma unroll
        for (int k = 0; k < 32; ++k) w0h[k] = p[k];
        p = w_ih + (size_t)G4H*H_ + (size_t)grow*H_ + q*32;
#pragma unroll
        for (int k = 0; k < 32; ++k) w1i[k] = p[k];
        p = w_hh + (size_t)G4H*H_ + (size_t)grow*H_ + q*32;
#pragma unroll
        for (int k = 0; k < 32; ++k) w1h[k] = p[k];
    }

    // ---- init: combined bias, c-state, h buffers (parity 1) ----
    if (tid < 128) {
        int l = tid >> 6, r = tid & 63;
        int gr = (r >> 4)*H_ + us + (r & 15);
        biasS[tid] = b_ih[l*G4H + gr] + b_hh[l*G4H + gr];
    }
    if (tid < 256) {
        int l = tid >> 7, i = tid & 127;
        int u = i >> 3, b = i & 7;
        cs[tid] = c0in[l*B_*H_ + (b0 + b)*H_ + us + u];
    }
    for (int i = tid; i < 2*8*H_; i += 512) {          // copy h0 input into parity-1 bufs
        int l = i >> 11;
        int rem = i & 2047;                            // b*256+k within slice
        float v = h0in[l*B_*H_ + b0*H_ + rem];
        (l ? h1buf : h0buf)[B_*H_ + b0*H_ + rem] = v;
    }
    __threadfence();
    grid.sync();

    for (int t = 0; t < T_; ++t) {
        const int par = t & 1;
        const float* hprev0 = h0buf + (1 - par)*B_*H_;
        const float* hprev1 = h1buf + (1 - par)*B_*H_;
        float* hcur0 = h0buf + par*B_*H_;
        float* hcur1 = h1buf + par*B_*H_;

        const int sb = q;                               // staging batch = wave id
        const float nd = done[t*B_ + b0 + sb] ? 0.f : 1.f;
        const int kk = j * 4;

        // ======== phase 0 : layer 0 ========
        {
            float4 va = *(const float4*)&x[((size_t)t*B_ + b0 + sb)*H_ + kk];
            float4 vb = *(const float4*)&hprev0[(b0 + sb)*H_ + kk];
            vb.x *= nd; vb.y *= nd; vb.z *= nd; vb.w *= nd;
            *(float4*)&tileA[sb*H_ + kk] = va;
            *(float4*)&tileB[sb*H_ + kk] = vb;
        }
        __syncthreads();
        compute_partials(w0i, w0h, tileA, tileB, part, q, j);
        __syncthreads();
        {   // reduce 8 waves + bias
            int r = tid >> 3, b = tid & 7;
            float g = biasS[0*64 + r];
#pragma unroll
            for (int qq = 0; qq < 8; ++qq) g += part[qq*576 + r*9 + b];
            gates[r*8 + b] = g;
        }
        __syncthreads();
        if (tid < 128) {
            int u = tid >> 3, b = tid & 7;
            float gi = gates[(u)*8 + b],  gf = gates[(16+u)*8 + b];
            float gg = gates[(32+u)*8 + b], go = gates[(48+u)*8 + b];
            float ii = 1.f/(1.f + expf(-gi));
            float ff = 1.f/(1.f + expf(-gf));
            float g2 = tanhf(gg);
            float oo = 1.f/(1.f + expf(-go));
            float ndb = done[t*B_ + b0 + b] ? 0.f : 1.f;
            float c = ff*(cs[tid]*ndb) + ii*g2;
            float h = oo*tanhf(c);
            cs[tid] = c;
            hcur0[(b0 + b)*H_ + us + u] = h;
            if (t == T_-1) {
                out[OUT_HT + (b0 + b)*H_ + us + u] = h;
                out[OUT_CT + (b0 + b)*H_ + us + u] = c;
            }
        }
        __threadfence();
        grid.sync();                                    // h0(t) now visible everywhere

        // head for step t-1 (h1buf[1-par] is stable this step)
        if (t > 0) head_for(t - 1, hprev1, b0, js, q, j, Wp, bp, Wb, bb, out);

        // ======== phase 1 : layer 1 ========
        {
            float4 va = *(const float4*)&hcur0[(b0 + sb)*H_ + kk];   // fresh, unmasked
            float4 vb = *(const float4*)&hprev1[(b0 + sb)*H_ + kk];
            vb.x *= nd; vb.y *= nd; vb.z *= nd; vb.w *= nd;
            *(float4*)&tileA[sb*H_ + kk] = va;
            *(float4*)&tileB[sb*H_ + kk] = vb;
        }
        __syncthreads();
        compute_partials(w1i, w1h, tileA, tileB, part, q, j);
        __syncthreads();
        {
            int r = tid >> 3, b = tid & 7;
            float g = biasS[1*64 + r];
#pragma unroll
            for (int qq = 0; qq < 8; ++qq) g += part[qq*576 + r*9 + b];
            gates[r*8 + b] = g;
        }
        __syncthreads();
        if (tid < 128) {
            int u = tid >> 3, b = tid & 7;
            float gi = gates[(u)*8 + b],  gf = gates[(16+u)*8 + b];
            float gg = gates[(32+u)*8 + b], go = gates[(48+u)*8 + b];
            float ii = 1.f/(1.f + expf(-gi));
            float ff = 1.f/(1.f + expf(-gf));
            float g2 = tanhf(gg);
            float oo = 1.f/(1.f + expf(-go));
            float ndb = done[t*B_ + b0 + b] ? 0.f : 1.f;
            float c = ff*(cs[128 + tid]*ndb) + ii*g2;
            float h = oo*tanhf(c);
            cs[128 + tid] = c;
            hcur1[(b0 + b)*H_ + us + u] = h;
            if (t == T_-1) {
                out[OUT_HT + B_*H_ + (b0 + b)*H_ + us + u] = h;
                out[OUT_CT + B_*H_ + (b0 + b)*H_ + us + u] = c;
            }
        }
        __threadfence();
        grid.sync();                                    // h1(t) now visible everywhere
    }

    // head for the final step
    head_for(T_-1, h1buf + ((T_-1) & 1)*B_*H_, b0, js, q, j, Wp, bp, Wb, bb, out);
}

__global__ void argmax_head(const float* __restrict__ logits, float* __restrict__ out_act)
{
    int i = blockIdx.x*256 + threadIdx.x;
    if (i >= TB_) return;
    const float* lg = logits + (size_t)i*A_;
    float best = lg[0]; int bi = 0;
#pragma unroll
    for (int a = 1; a < A_; ++a) { float v = lg[a]; if (v > best) { best = v; bi = a; } }
    out_act[i] = (float)bi;
}

extern "C" void kernel_launch(void* const* d_in, const int* in_sizes, int n_in,
                              void* d_out, int out_size, void* d_ws, size_t ws_size,
                              hipStream_t stream)
{
    const float* x    = (const float*)d_in[0];
    const int*   done = (const int*)  d_in[1];
    const float* h0   = (const float*)d_in[2];
    const float* c0   = (const float*)d_in[3];
    const float* w_ih = (const float*)d_in[4];
    const float* w_hh = (const float*)d_in[5];
    const float* b_ih = (const float*)d_in[6];
    const float* b_hh = (const float*)d_in[7];
    const float* Wp   = (const float*)d_in[8];
    const float* bp   = (const float*)d_in[9];
    const float* Wb   = (const float*)d_in[10];
    const float* bb   = (const float*)d_in[11];
    float* out   = (float*)d_out;
    float* h0buf = (float*)d_ws;                 // [2][B][H]
    float* h1buf = h0buf + 2*B_*H_;              // [2][B][H]

    void* args[] = { (void*)&x, (void*)&done, (void*)&h0, (void*)&c0,
                     (void*)&w_ih, (void*)&w_hh, (void*)&b_ih, (void*)&b_hh,
                     (void*)&Wp, (void*)&bp, (void*)&Wb, (void*)&bb,
                     (void*)&out, (void*)&h0buf, (void*)&h1buf };
    hipLaunchCooperativeKernel((void*)lstm_scan, dim3(256), dim3(512), args, 0, stream);

    argmax_head<<<TB_/256, 256, 0, stream>>>(out, out + OUT_ACT);
}